// Round 3
// baseline (1467.063 us; speedup 1.0000x reference)
//
#include <hip/hip_runtime.h>
#include <math.h>

#define FRAME 128
#define HOPW 64
#define SLEN 65536
#define IRLEN 1024
#define NFB 1006          // (65536 - 1151 - 1) / 64
#define RMASK 2047
#define PI_D 3.14159265358979323846

__device__ __forceinline__ float clip1(float v) { return fminf(1.0f, fmaxf(-1.0f, v)); }

// Raw barrier: drains LDS ops only; global loads/stores stay in flight.
__device__ __forceinline__ void loop_barrier() {
    __builtin_amdgcn_sched_barrier(0);
    asm volatile("s_waitcnt lgkmcnt(0)" ::: "memory");
    __builtin_amdgcn_s_barrier();
    __builtin_amdgcn_sched_barrier(0);
}

// Fused kernel: IR-scaling prologue + sequential howling loop.
// 768 threads = 12 waves. FMA layout: kg = tid/192 (32-tap group, wave-uniform),
// ob = tid%192 -> 6 conv outputs; constant 37-float IR window in VGPRs.
// w_i lives in registers (w0,w1) in EVERY wave (computed redundantly post-barrier).
__global__ __launch_bounds__(768) void howl_fused(const float* __restrict__ x,
                                                  const float* __restrict__ ir,
                                                  float* __restrict__ out) {
    __shared__ float ring[2048];         // circular raw/updated x window
    __shared__ float part[2][4][1152];   // double-buffered per-kg conv partials
    __shared__ float irl[IRLEN];
    __shared__ float red1[1024];
    __shared__ float red2[1024];
    __shared__ float invfs;

    const int tid = threadIdx.x;
    const int lane = tid & 63;
    const int wvid = tid >> 6;
    const int kg = tid / 192;
    const int ob = tid % 192;
    const int q = ob * 6;
    const int lo = q - kg * 32 - 31;

    // ---- prologue: stage IR + raw x window ----
    for (int idx = tid; idx < IRLEN; idx += 768) irl[idx] = ir[idx];
    for (int idx = tid; idx < 1216; idx += 768) ring[idx] = x[idx];  // raw (frame 0 reads raw)
    if (tid >= 513) { red1[tid] = -INFINITY; red2[tid] = 0.f; }
    if (tid < 256) { red1[768 + tid] = -INFINITY; red2[768 + tid] = 0.f; }
    __syncthreads();

    // ---- DFT power spectrum (4-way ILP recurrence, double precision) ----
    if (tid < 513) {
        double th = -2.0 * PI_D * (double)tid / 1024.0;
        double c4 = cos(4.0 * th), s4 = sin(4.0 * th);
        double wr0 = 1.0,           wi0 = 0.0;
        double wr1 = cos(th),       wi1 = sin(th);
        double wr2 = cos(2.0 * th), wi2 = sin(2.0 * th);
        double wr3 = cos(3.0 * th), wi3 = sin(3.0 * th);
        double ar0 = 0, ai0 = 0, ar1 = 0, ai1 = 0, ar2 = 0, ai2 = 0, ar3 = 0, ai3 = 0;
        for (int m = 0; m < 256; ++m) {
            double x0 = irl[4 * m], x1 = irl[4 * m + 1], x2 = irl[4 * m + 2], x3 = irl[4 * m + 3];
            ar0 += x0 * wr0; ai0 += x0 * wi0;
            ar1 += x1 * wr1; ai1 += x1 * wi1;
            ar2 += x2 * wr2; ai2 += x2 * wi2;
            ar3 += x3 * wr3; ai3 += x3 * wi3;
            double t;
            t = wr0 * c4 - wi0 * s4; wi0 = wr0 * s4 + wi0 * c4; wr0 = t;
            t = wr1 * c4 - wi1 * s4; wi1 = wr1 * s4 + wi1 * c4; wr1 = t;
            t = wr2 * c4 - wi2 * s4; wi2 = wr2 * s4 + wi2 * c4; wr2 = t;
            t = wr3 * c4 - wi3 * s4; wi3 = wr3 * s4 + wi3 * c4; wr3 = t;
        }
        double re = (ar0 + ar1) + (ar2 + ar3);
        double im = (ai0 + ai1) + (ai2 + ai3);
        float mag = (float)sqrt(re * re + im * im);
        float pw = mag * mag;
        double ph = atan2(im, re);
        int ok = (ph > -0.1 && ph < 0.1) ? 1 : 0;
        red1[tid] = ok ? pw : -INFINITY;
        red2[tid] = pw;
    }
    __syncthreads();
    for (int s = 512; s > 0; s >>= 1) {
        if (tid < s) {
            red1[tid] = fmaxf(red1[tid], red1[tid + s]);
            red2[tid] = red2[tid] + red2[tid + s];
        }
        __syncthreads();
    }
    if (tid == 0) {
        float peak = red1[0];
        float MLG = red2[0] / 513.0f;
        float MSG = -10.0f * log10f(peak / MLG);
        float target_gain = MSG + 2.0f;
        float mean_gain = 10.0f * log10f(MLG);
        invfs = powf(0.5f, (target_gain - mean_gain) / 6.0f);
    }
    __syncthreads();

    const float fbc = invfs;
    float wir[37];
#pragma unroll
    for (int j = 0; j < 37; ++j) {
        int idx = lo + j;
        wir[j] = (idx >= 0 && idx < IRLEN) ? irl[idx] / fbc : 0.f;
    }

    // hann window values + initial frame, all in registers (every wave)
    const float hv0 = (float)(0.5 * (1.0 - cos(PI_D * (double)lane / 64.0)));
    const float hv1 = (float)(0.5 * (1.0 - cos(PI_D * (double)(64 + lane) / 64.0)));
    float w0 = hv0 * ring[lane];        // w_0[lane]
    float w1 = hv1 * ring[64 + lane];   // w_0[64+lane]
    float pw1 = 0.f;                    // w_{i-1}[64+lane]
    float xv = 0.f;
    if (wvid == 1) xv = x[1216 + lane]; // prefetch for iter-0 commit
    const int lbase = (kg & 1) * 32 + 31;
    __syncthreads();

    int pb = 0;
#pragma unroll 1
    for (int i = 0; i < NFB; ++i) {
        const int base = i * HOPW;

        // --- phase B ---
        if (wvid == 0) {
            out[base + lane] = clip1(w0 + pw1);          // OLA output block i (regs only)
        } else if (wvid == 1) {
            int pos = base + 1216 + lane;
            if (pos < SLEN) ring[pos & RMASK] = clip1(xv);  // commit prev prefetch
            int npos = pos + HOPW;
            xv = (npos < SLEN) ? x[npos] : 0.f;             // stays in flight across barriers
        }

        // deferred tail: apply ALL of conv_{i-1} to ring (overlapped with FMA)
        if (i > 0) {
            const float* pp = &part[pb ^ 1][0][0];
            {
                int p = tid;
                int slot = (base + p) & RMASK;
                float s = pp[p] + pp[1152 + p] + pp[2304 + p] + pp[3456 + p];
                ring[slot] = clip1(ring[slot] + s);
            }
            if (tid >= 384) {
                int p = 384 + tid;   // 768 + (tid-384)
                int slot = (base + p) & RMASK;
                float s = pp[p] + pp[1152 + p] + pp[2304 + p] + pp[3456 + p];
                ring[slot] = clip1(ring[slot] + s);
            }
        }

        // conv partials for frame i: w scalar straight from registers via readlane
        float wsrc = (kg < 2) ? w0 : w1;
        float a0 = 0, a1 = 0, a2 = 0, a3 = 0, a4 = 0, a5 = 0;
#pragma unroll
        for (int kk = 0; kk < 32; ++kk) {
            float s = __int_as_float(__builtin_amdgcn_readlane(__float_as_int(wsrc), lbase - kk));
            a0 = fmaf(s, wir[kk + 0], a0);
            a1 = fmaf(s, wir[kk + 1], a1);
            a2 = fmaf(s, wir[kk + 2], a2);
            a3 = fmaf(s, wir[kk + 3], a3);
            a4 = fmaf(s, wir[kk + 4], a4);
            a5 = fmaf(s, wir[kk + 5], a5);
        }
        float* pw = &part[pb][kg][q];
        *(float2*)(pw + 0) = make_float2(a0, a1);
        *(float2*)(pw + 2) = make_float2(a2, a3);
        *(float2*)(pw + 4) = make_float2(a4, a5);

        loop_barrier();

        // --- post: EVERY wave redundantly computes w_{i+1}[0:128] into regs ---
        {
            const float* pc = &part[pb][0][0];
            int c0 = lane, c1 = 64 + lane;
            float s0 = pc[c0] + pc[1152 + c0] + pc[2304 + c0] + pc[3456 + c0];
            float s1 = pc[c1] + pc[1152 + c1] + pc[2304 + c1] + pc[3456 + c1];
            float v0 = clip1(ring[(base + 64 + c0) & RMASK] + s0);
            float v1 = clip1(ring[(base + 64 + c1) & RMASK] + s1);
            pw1 = w1;
            w0 = hv0 * v0;
            w1 = hv1 * v1;
        }

        loop_barrier();
        pb ^= 1;
    }

    // ---- epilogue: last frame's OLA blocks + zero tail ----
    if (wvid == 0) {
        out[64384 + lane] = clip1(w0 + pw1);
        out[64448 + lane] = clip1(w1);
    }
    for (int idx = 64512 + tid; idx < SLEN; idx += 768) out[idx] = 0.f;
}

extern "C" void kernel_launch(void* const* d_in, const int* in_sizes, int n_in,
                              void* d_out, int out_size, void* d_ws, size_t ws_size,
                              hipStream_t stream) {
    const float* x = (const float*)d_in[0];
    const float* ir = (const float*)d_in[1];
    float* out = (float*)d_out;
    (void)d_ws; (void)ws_size; (void)in_sizes; (void)n_in; (void)out_size;

    hipLaunchKernelGGL(howl_fused, dim3(1), dim3(768), 0, stream, x, ir, out);
}

// Round 4
// 1121.600 us; speedup vs baseline: 1.3080x; 1.3080x over previous
//
#include <hip/hip_runtime.h>
#include <math.h>

#define FRAME 128
#define HOPW 64
#define SLEN 65536
#define IRLEN 1024
#define NFB 1006          // (65536 - 1151 - 1) / 64
#define RMASK 2047
#define PI_D 3.14159265358979323846

typedef float f32x2 __attribute__((ext_vector_type(2)));

__device__ __forceinline__ float clip1(float v) { return fminf(1.0f, fmaxf(-1.0f, v)); }

// Raw barrier: drains LDS ops only; global loads/stores stay in flight.
__device__ __forceinline__ void loop_barrier() {
    __builtin_amdgcn_sched_barrier(0);
    asm volatile("s_waitcnt lgkmcnt(0)" ::: "memory");
    __builtin_amdgcn_s_barrier();
    __builtin_amdgcn_sched_barrier(0);
}

// Fused kernel: IR-scaling prologue + sequential howling loop (round-2 structure).
// 768 threads = 12 waves. kg = tid/192 (32-tap group, wave-uniform), ob = tid%192
// -> 6 conv outputs as 3 packed f32x2 accumulators; IR window pre-marshalled as
// 36 f32x2 pair-registers so v_pk_fma_f32 operands are aligned VGPR pairs.
__global__ __launch_bounds__(768) void howl_fused(const float* __restrict__ x,
                                                  const float* __restrict__ ir,
                                                  float* __restrict__ out) {
    __shared__ float ring[2048];         // circular raw/updated x window
    __shared__ float part[2][4][1152];   // double-buffered per-kg conv partials
    __shared__ float irl[IRLEN];
    __shared__ float wlds[FRAME];        // current windowed frame w_i
    __shared__ float winv[FRAME];        // hann window
    __shared__ float tailb[HOPW];        // w_{i-1}[64:128]
    __shared__ float red1[1024];
    __shared__ float red2[1024];
    __shared__ float invfs;

    const int tid = threadIdx.x;
    const int lane = tid & 63;
    const int wvid = tid >> 6;
    const int kg = tid / 192;
    const int ob = tid % 192;
    const int q = ob * 6;
    const int lo = q - kg * 32 - 31;

    // ---- prologue: stage IR + raw x window + window table ----
    for (int idx = tid; idx < IRLEN; idx += 768) irl[idx] = ir[idx];
    for (int idx = tid; idx < 1216; idx += 768) ring[idx] = x[idx];  // raw (frame 0 reads raw)
    if (tid < FRAME) winv[tid] = (float)(0.5 * (1.0 - cos(PI_D * (double)tid / 64.0)));
    if (tid < HOPW) tailb[tid] = 0.f;
    if (tid >= 513) { red1[tid] = -INFINITY; red2[tid] = 0.f; }
    if (tid < 256) { red1[768 + tid] = -INFINITY; red2[768 + tid] = 0.f; }
    __syncthreads();

    // ---- DFT power spectrum (4-way ILP recurrence, double precision) ----
    if (tid < 513) {
        double th = -2.0 * PI_D * (double)tid / 1024.0;
        double c4 = cos(4.0 * th), s4 = sin(4.0 * th);
        double wr0 = 1.0,           wi0 = 0.0;
        double wr1 = cos(th),       wi1 = sin(th);
        double wr2 = cos(2.0 * th), wi2 = sin(2.0 * th);
        double wr3 = cos(3.0 * th), wi3 = sin(3.0 * th);
        double ar0 = 0, ai0 = 0, ar1 = 0, ai1 = 0, ar2 = 0, ai2 = 0, ar3 = 0, ai3 = 0;
        for (int m = 0; m < 256; ++m) {
            double x0 = irl[4 * m], x1 = irl[4 * m + 1], x2 = irl[4 * m + 2], x3 = irl[4 * m + 3];
            ar0 += x0 * wr0; ai0 += x0 * wi0;
            ar1 += x1 * wr1; ai1 += x1 * wi1;
            ar2 += x2 * wr2; ai2 += x2 * wi2;
            ar3 += x3 * wr3; ai3 += x3 * wi3;
            double t;
            t = wr0 * c4 - wi0 * s4; wi0 = wr0 * s4 + wi0 * c4; wr0 = t;
            t = wr1 * c4 - wi1 * s4; wi1 = wr1 * s4 + wi1 * c4; wr1 = t;
            t = wr2 * c4 - wi2 * s4; wi2 = wr2 * s4 + wi2 * c4; wr2 = t;
            t = wr3 * c4 - wi3 * s4; wi3 = wr3 * s4 + wi3 * c4; wr3 = t;
        }
        double re = (ar0 + ar1) + (ar2 + ar3);
        double im = (ai0 + ai1) + (ai2 + ai3);
        float mag = (float)sqrt(re * re + im * im);
        float pw = mag * mag;
        double ph = atan2(im, re);
        int ok = (ph > -0.1 && ph < 0.1) ? 1 : 0;
        red1[tid] = ok ? pw : -INFINITY;
        red2[tid] = pw;
    }
    __syncthreads();
    for (int s = 512; s > 0; s >>= 1) {
        if (tid < s) {
            red1[tid] = fmaxf(red1[tid], red1[tid + s]);
            red2[tid] = red2[tid] + red2[tid + s];
        }
        __syncthreads();
    }
    if (tid == 0) {
        float peak = red1[0];
        float MLG = red2[0] / 513.0f;
        float MSG = -10.0f * log10f(peak / MLG);
        float target_gain = MSG + 2.0f;
        float mean_gain = 10.0f * log10f(MLG);
        invfs = powf(0.5f, (target_gain - mean_gain) / 6.0f);
    }
    __syncthreads();

    const float fbc = invfs;
    // IR window as PAIR registers: wp[j] = (wir[j], wir[j+1]) -> pk_fma operands.
    f32x2 wp[36];
#pragma unroll
    for (int j = 0; j < 36; ++j) {
        int i0 = lo + j, i1 = lo + j + 1;
        float e0 = (i0 >= 0 && i0 < IRLEN) ? irl[i0] / fbc : 0.f;
        float e1 = (i1 >= 0 && i1 < IRLEN) ? irl[i1] / fbc : 0.f;
        wp[j] = (f32x2){e0, e1};
    }

    float xv = 0.f;
    if (wvid == 1) xv = x[1216 + lane];                 // prefetch for iter-0 commit
    if (tid < FRAME) wlds[tid] = winv[tid] * ring[tid]; // w_0 from raw x
    __syncthreads();

    float* const p0 = &part[0][0][0];
    float* const p1 = &part[1][0][0];

    auto body = [&](int i, float* pcur, const float* pprev) {
#pragma clang fp contract(fast)
        const int base = i * HOPW;

        float wreg = wlds[kg * 32 + (lane & 31)];  // lane j holds w[kg*32+j]

        // wave 0: overlap-add output block i ; wave 1: x commit + prefetch
        if (wvid == 0) {
            float w0v = wlds[lane];
            float w1v = wlds[64 + lane];
            out[base + lane] = clip1(w0v + tailb[lane]);
            tailb[lane] = w1v;
        } else if (wvid == 1) {
            int pos = base + 1216 + lane;
            if (pos < SLEN) ring[pos & RMASK] = clip1(xv);  // commit prev prefetch
            int npos = pos + HOPW;
            xv = (npos < SLEN) ? x[npos] : 0.f;             // stays in flight across barriers
        }

        // deferred tail: apply conv_{i-1} p in [128,1152) to ring (overlaps FMA)
        if (i > 0) {
            {
                int p = 128 + tid;
                int slot = (base + p) & RMASK;
                float s = pprev[p] + pprev[1152 + p] + pprev[2304 + p] + pprev[3456 + p];
                ring[slot] = clip1(ring[slot] + s);
            }
            if (tid >= 256 && tid < 512) {
                int p = 896 + (tid - 256);
                int slot = (base + p) & RMASK;
                float s = pprev[p] + pprev[1152 + p] + pprev[2304 + p] + pprev[3456 + p];
                ring[slot] = clip1(ring[slot] + s);
            }
        }

        // conv partials for frame i: packed f32x2 accumulators (v_pk_fma_f32),
        // scalar w tap from readlane (SGPR, broadcast via op_sel).
        f32x2 a01 = {0.f, 0.f}, a23 = {0.f, 0.f}, a45 = {0.f, 0.f};
#pragma unroll
        for (int kk = 0; kk < 32; ++kk) {
            float s = __int_as_float(__builtin_amdgcn_readlane(__float_as_int(wreg), 31 - kk));
            f32x2 sv = {s, s};
            a01 = sv * wp[kk + 0] + a01;
            a23 = sv * wp[kk + 2] + a23;
            a45 = sv * wp[kk + 4] + a45;
        }
        float* pw = pcur + kg * 1152 + q;
        *(f32x2*)(pw + 0) = a01;
        *(f32x2*)(pw + 2) = a23;
        *(f32x2*)(pw + 4) = a45;

        loop_barrier();

        // head: conv_i outputs p in [0,128) -> ring RMW + next frame w_{i+1}
        if (tid < 128) {
            int slot = (base + 64 + tid) & RMASK;
            float s = pcur[tid] + pcur[1152 + tid] + pcur[2304 + tid] + pcur[3456 + tid];
            float v = clip1(ring[slot] + s);
            ring[slot] = v;
            wlds[tid] = winv[tid] * v;
        }

        loop_barrier();
    };

#pragma unroll 1
    for (int i = 0; i < NFB; i += 2) {   // NFB even: pb is compile-time per half
        body(i, p0, p1);
        body(i + 1, p1, p0);
    }

    // ---- epilogue: last frame's OLA blocks + zero tail ----
    if (tid < 64) out[64384 + tid] = clip1(wlds[tid] + tailb[tid]);
    else if (tid < 128) out[64384 + tid] = clip1(wlds[tid]);
    for (int idx = 64512 + tid; idx < SLEN; idx += 768) out[idx] = 0.f;
}

extern "C" void kernel_launch(void* const* d_in, const int* in_sizes, int n_in,
                              void* d_out, int out_size, void* d_ws, size_t ws_size,
                              hipStream_t stream) {
    const float* x = (const float*)d_in[0];
    const float* ir = (const float*)d_in[1];
    float* out = (float*)d_out;
    (void)d_ws; (void)ws_size; (void)in_sizes; (void)n_in; (void)out_size;

    hipLaunchKernelGGL(howl_fused, dim3(1), dim3(768), 0, stream, x, ir, out);
}